// Round 5
// baseline (25782.718 us; speedup 1.0000x reference)
//
#include <hip/hip_runtime.h>
#include <math.h>

#define T_LEN 4096
#define EDIM  256
#define HDIM  512
#define NTAGS 50
#define SENTW 0xFFFFFFFFu

__device__ __forceinline__ float sigm(float x) { return 1.0f / (1.0f + expf(-x)); }
__device__ __forceinline__ float u2f(unsigned u) { union { unsigned i; float f; } v; v.i = u; return v.f; }

// ---------------------------------------------------------------------------
// Persistent bidirectional LSTM scan (f32). Wave-independent design:
//   64 WGs x 256 threads; blocks 0..31 forward, 32..63 backward.
//   Wave wv of WG g owns 4 hidden units  U = g*16 + wv*4 + j, j=0..3
//   => 16 gate rows R(q,j) = q*512 + g*16 + wv*4 + j   (q = gate i,f,g,o).
//   LANE owns columns: h cols [lane*8,+8), emb cols [lane*4,+4).
//   => matvec is 128+64 pure v_fmac from register weights and the lane's own
//      polled h / emb values. NO readlane, NO LDS, NO __syncthreads.
// Reduction: folding butterfly. Round k (masks 1,2,4,8) folds acc-index bit
// (3-k... acc count 16->8->4->2->1) against lane bit k:
//   mine  = bit_k ? r[i+half] : r[i]
//   other = bit_k ? r[i]      : r[i+half]
//   r[i]  = mine + shfl_xor(other, 1<<k)
// After 4 rounds lane l holds row r = 8*b0+4*b1+2*b2+b3 (b=lane bits) summed
// over lane bits 0..3; two more xor(16)/xor(32) adds give the full 64-lane
// sum. Gates of unit j sit on consecutive lanes base=l&60 at offsets
// {0:i, 1:g, 2:f, 3:o}; all lanes redundantly compute unit j(l)=2*b2+b3.
// Sync: hs[t] doubles as data+flag (memset 0xFF = -NaN, unproducible by
// o*tanh(c), finite). Producers: relaxed agent-scope stores (lanes 0,4,8,12).
// Consumers: poll own 4 u64 words with relaxed agent loads. Same-location
// coherence only; no fences, no cache-wide ops.
// ---------------------------------------------------------------------------
__global__ __launch_bounds__(256, 1) void lstm_scan(
    const int* __restrict__ sent, const float* __restrict__ emb,
    const float* __restrict__ Wih_f, const float* __restrict__ Whh_f,
    const float* __restrict__ bih_f, const float* __restrict__ bhh_f,
    const float* __restrict__ Wih_b, const float* __restrict__ Whh_b,
    const float* __restrict__ bih_b, const float* __restrict__ bhh_b,
    float* hsf, float* hsb)
{
    const int tid  = threadIdx.x;
    const int lane = tid & 63;
    const int wv   = tid >> 6;
    const int dir  = blockIdx.x >> 5;
    const int g    = blockIdx.x & 31;

    const float* Wih = dir ? Wih_b : Wih_f;
    const float* Whh = dir ? Whh_b : Whh_f;
    const float* bih = dir ? bih_b : bih_f;
    const float* bhh = dir ? bhh_b : bhh_f;
    float* hs = dir ? hsb : hsf;

    // Register weights: wh[i][0..7] = Whh[R(i)][lane*8+m], wx[i][0..3].
    float wh[16][8], wx[16][4];
    #pragma unroll
    for (int i = 0; i < 16; ++i) {
        const int q = i >> 2, j = i & 3;
        const int R = q * 512 + g * 16 + wv * 4 + j;
        float4 a = *(const float4*)(Whh + (size_t)R * HDIM + lane * 8);
        float4 b = *(const float4*)(Whh + (size_t)R * HDIM + lane * 8 + 4);
        wh[i][0] = a.x; wh[i][1] = a.y; wh[i][2] = a.z; wh[i][3] = a.w;
        wh[i][4] = b.x; wh[i][5] = b.y; wh[i][6] = b.z; wh[i][7] = b.w;
        float4 c = *(const float4*)(Wih + (size_t)R * EDIM + lane * 4);
        wx[i][0] = c.x; wx[i][1] = c.y; wx[i][2] = c.z; wx[i][3] = c.w;
    }

    // Bias of the row this lane ends up holding after the fold.
    const int b0 = lane & 1, b1 = (lane >> 1) & 1, b2 = (lane >> 2) & 1, b3 = (lane >> 3) & 1;
    const int r_fin = 8 * b0 + 4 * b1 + 2 * b2 + b3;
    const int R_fin = (r_fin >> 2) * 512 + g * 16 + wv * 4 + (r_fin & 3);
    const float bias_fin = bih[R_fin] + bhh[R_fin];

    // Unit this lane (redundantly) activates, and the gate-gather base.
    const int j_act = 2 * b2 + b3;
    const int gbase = lane & 60;
    const bool is_store = ((lane & 3) == 0) && (lane < 16);
    const int u_glob = g * 16 + wv * 4 + j_act;

    float c_state = 0.0f;

    // Embedding pipeline: lane holds emb[sent[t]][lane*4 + i].
    float4 ecur;
    {
        int t0 = dir ? (T_LEN - 1) : 0;
        ecur = *(const float4*)(emb + (size_t)sent[t0] * EDIM + lane * 4);
    }

    for (int s = 0; s < T_LEN; ++s) {
        const int t = dir ? (T_LEN - 1 - s) : s;

        // 1. Issue first poll sample ASAP (flies under x-part + prefetch).
        const unsigned long long* hp = nullptr;
        unsigned long long v[4];
        if (s > 0) {
            const int tp = dir ? (t + 1) : (t - 1);
            hp = (const unsigned long long*)(hs + (size_t)tp * HDIM) + lane * 4;
            #pragma unroll
            for (int i = 0; i < 4; ++i)
                v[i] = __hip_atomic_load(hp + i, __ATOMIC_RELAXED, __HIP_MEMORY_SCOPE_AGENT);
        }

        // 2. Prefetch next step's embedding values (h-independent).
        float4 enext = make_float4(0.f, 0.f, 0.f, 0.f);
        if (s + 1 < T_LEN) {
            int tn = dir ? (t - 1) : (t + 1);
            enext = *(const float4*)(emb + (size_t)sent[tn] * EDIM + lane * 4);
        }

        // 3. x-part: 64 pure FMAs from registers (overlaps in-flight polls).
        float r[16];
        #pragma unroll
        for (int i = 0; i < 16; ++i) {
            r[i] = wx[i][0] * ecur.x;
            r[i] = fmaf(wx[i][1], ecur.y, r[i]);
            r[i] = fmaf(wx[i][2], ecur.z, r[i]);
            r[i] = fmaf(wx[i][3], ecur.w, r[i]);
        }

        if (s > 0) {
            // 4. Resolve poll: reload until this lane's 8 words are real.
            for (;;) {
                bool bad = false;
                #pragma unroll
                for (int i = 0; i < 4; ++i)
                    bad |= ((unsigned)v[i] == SENTW) || ((unsigned)(v[i] >> 32) == SENTW);
                if (!bad) break;
                #pragma unroll
                for (int i = 0; i < 4; ++i)
                    v[i] = __hip_atomic_load(hp + i, __ATOMIC_RELAXED, __HIP_MEMORY_SCOPE_AGENT);
            }
            float h8[8];
            #pragma unroll
            for (int i = 0; i < 4; ++i) {
                h8[2 * i]     = u2f((unsigned)v[i]);
                h8[2 * i + 1] = u2f((unsigned)(v[i] >> 32));
            }
            // 5. h-part: 128 pure FMAs.
            #pragma unroll
            for (int i = 0; i < 16; ++i) {
                #pragma unroll
                for (int m = 0; m < 8; ++m)
                    r[i] = fmaf(wh[i][m], h8[m], r[i]);
            }
        }

        // 6. Folding butterfly reduction (16 rows x 64 lanes).
        #pragma unroll
        for (int k = 0; k < 4; ++k) {
            const int half = 8 >> k;
            const bool sel = (lane >> k) & 1;
            #pragma unroll
            for (int i = 0; i < half; ++i) {
                float mine  = sel ? r[i + half] : r[i];
                float other = sel ? r[i]        : r[i + half];
                r[i] = mine + __shfl_xor(other, 1 << k, 64);
            }
        }
        float tot = r[0];
        tot += __shfl_xor(tot, 16, 64);
        tot += __shfl_xor(tot, 32, 64);
        tot += bias_fin;

        // 7. Gather gates of unit j_act (consecutive lanes: i,g,f,o).
        float gi = __shfl(tot, gbase + 0, 64);
        float gg = __shfl(tot, gbase + 1, 64);
        float gf = __shfl(tot, gbase + 2, 64);
        float go = __shfl(tot, gbase + 3, 64);

        float iv = sigm(gi), fv = sigm(gf);
        float gv = tanhf(gg), ov = sigm(go);
        c_state = fv * c_state + iv * gv;
        float h = ov * tanhf(c_state);

        // 8. Publish (4 lanes per wave, relaxed agent store).
        if (is_store)
            __hip_atomic_store(hs + (size_t)t * HDIM + u_glob, h,
                               __ATOMIC_RELAXED, __HIP_MEMORY_SCOPE_AGENT);

        ecur = enext;
    }
}

// ---------------------------------------------------------------------------
// tag_space[t] = [hs_f[t] | hs_b[t]] @ W_out^T + b_out  (f32 out)
// ---------------------------------------------------------------------------
__global__ __launch_bounds__(256) void out_gemm(
    const float* __restrict__ hsf, const float* __restrict__ hsb,
    const float* __restrict__ Wout, const float* __restrict__ bout,
    float* __restrict__ out)
{
    const int t   = blockIdx.x;
    const int tid = threadIdx.x;
    __shared__ float h2[1024];

    if (tid < 128)
        *(float4*)(h2 + tid * 4) = *(const float4*)(hsf + (size_t)t * HDIM + tid * 4);
    else
        *(float4*)(h2 + 512 + (tid - 128) * 4) = *(const float4*)(hsb + (size_t)t * HDIM + (tid - 128) * 4);
    __syncthreads();

    const int wv = tid >> 6, lane = tid & 63;
    for (int tag = wv; tag < NTAGS; tag += 4) {
        const float4* wr = (const float4*)(Wout + (size_t)tag * (2 * HDIM));
        float p = 0.0f;
        #pragma unroll
        for (int c = lane; c < 256; c += 64) {
            float4 wv4 = wr[c];
            float4 hv  = *(const float4*)(h2 + c * 4);
            p += wv4.x * hv.x + wv4.y * hv.y + wv4.z * hv.z + wv4.w * hv.w;
        }
        p += __shfl_down(p, 32, 64);
        p += __shfl_down(p, 16, 64);
        p += __shfl_down(p, 8, 64);
        p += __shfl_down(p, 4, 64);
        p += __shfl_down(p, 2, 64);
        p += __shfl_down(p, 1, 64);
        if (lane == 0) out[(size_t)t * NTAGS + tag] = p + bout[tag];
    }
}

// ---------------------------------------------------------------------------
extern "C" void kernel_launch(void* const* d_in, const int* in_sizes, int n_in,
                              void* d_out, int out_size, void* d_ws, size_t ws_size,
                              hipStream_t stream)
{
    const int*   sent  = (const int*)d_in[0];
    const float* emb   = (const float*)d_in[1];
    const float* Wih_f = (const float*)d_in[2];
    const float* Whh_f = (const float*)d_in[3];
    const float* bih_f = (const float*)d_in[4];
    const float* bhh_f = (const float*)d_in[5];
    const float* Wih_b = (const float*)d_in[6];
    const float* Whh_b = (const float*)d_in[7];
    const float* bih_b = (const float*)d_in[8];
    const float* bhh_b = (const float*)d_in[9];
    const float* Wout  = (const float*)d_in[10];
    const float* bout  = (const float*)d_in[11];
    float* out = (float*)d_out;

    char* ws = (char*)d_ws;
    // Workspace: hsf [4096*512 f32] @ 0 (8 MiB), hsb @ 8 MiB. Both double as
    // sync flags: sentinel-fill with 0xFF (-NaN, never produced by o*tanh(c)).
    float* hsf = (float*)(ws);
    float* hsb = (float*)(ws + 8388608);
    hipMemsetAsync(ws, 0xFF, 16777216, stream);

    lstm_scan<<<64, 256, 0, stream>>>(sent, emb,
                                      Wih_f, Whh_f, bih_f, bhh_f,
                                      Wih_b, Whh_b, bih_b, bhh_b,
                                      hsf, hsb);
    out_gemm<<<T_LEN, 256, 0, stream>>>(hsf, hsb, Wout, bout, out);
}